// Round 1
// baseline (424.312 us; speedup 1.0000x reference)
//
#include <hip/hip_runtime.h>

#define B_ 4
#define T_ 2048
#define C_ 1024
#define H_ 16
#define D_ 64
#define M_ (B_*T_)   // 8192 rows

typedef unsigned short u16;
typedef __attribute__((ext_vector_type(8))) short short8;
typedef __attribute__((ext_vector_type(8))) unsigned short ushort8_t;
typedef __attribute__((ext_vector_type(4))) unsigned short ushort4_t;
typedef __attribute__((ext_vector_type(4))) float floatx4;

__device__ __forceinline__ u16 f2bf(float f) {
  union { float f; unsigned u; } v; v.f = f;
  unsigned r = v.u + 0x7fffu + ((v.u >> 16) & 1u);
  return (u16)(r >> 16);
}

__device__ __forceinline__ void gload16(const void* g, void* l) {
  __builtin_amdgcn_global_load_lds((__attribute__((address_space(1))) void*)(g),
                                   (__attribute__((address_space(3))) void*)(l),
                                   16, 0, 0);
}

// ---------------- x -> bf16 ----------------
__global__ __launch_bounds__(256) void convx_k(const float* __restrict__ x,
                                               u16* __restrict__ o) {
  int i = (blockIdx.x * 256 + threadIdx.x) * 4;
  floatx4 v = *(const floatx4*)(x + i);
  ushort4_t r;
#pragma unroll
  for (int j = 0; j < 4; ++j) r[j] = f2bf(v[j]);
  *(ushort4_t*)(o + i) = r;
}

// ------------- W (K x N) -> WT (N x K) bf16, LDS-tiled transpose -------------
__global__ __launch_bounds__(256) void wconv_k(const float* __restrict__ W0,
                                               const float* __restrict__ W1,
                                               const float* __restrict__ W2,
                                               const float* __restrict__ W3,
                                               u16* __restrict__ WT) {
  __shared__ float tile[64][65];
  const float* W = blockIdx.z == 0 ? W0 : blockIdx.z == 1 ? W1 : blockIdx.z == 2 ? W2 : W3;
  u16* Wt = WT + (size_t)blockIdx.z * (C_ * C_);
  int k0 = blockIdx.x * 64, n0 = blockIdx.y * 64;
  int t = threadIdx.x;
  int r = t >> 2, c0 = (t & 3) * 16;
#pragma unroll
  for (int j = 0; j < 4; ++j) {
    floatx4 v = *(const floatx4*)(W + (size_t)(k0 + r) * C_ + n0 + c0 + j * 4);
#pragma unroll
    for (int jj = 0; jj < 4; ++jj) tile[r][c0 + j * 4 + jj] = v[jj];
  }
  __syncthreads();
  ushort8_t o0, o1;
#pragma unroll
  for (int j = 0; j < 8; ++j) o0[j] = f2bf(tile[c0 + j][r]);
#pragma unroll
  for (int j = 0; j < 8; ++j) o1[j] = f2bf(tile[c0 + 8 + j][r]);
  *(ushort8_t*)(Wt + (size_t)(n0 + r) * C_ + k0 + c0) = o0;
  *(ushort8_t*)(Wt + (size_t)(n0 + r) * C_ + k0 + c0 + 8) = o1;
}

// ------------- GEMM: C[M,N] = A[M,K] @ WT[N,K]^T + bias, N=K=1024 -------------
// 128x128 tile, BK=32, 4 waves (2x2), 4x4 16x16x32 frags per wave.
template <int OUTF32>
__global__ __launch_bounds__(256, 2) void gemm_k(const u16* __restrict__ A,
                                                 const u16* __restrict__ Wt,
                                                 const float* __restrict__ bias,
                                                 void* __restrict__ Cout, float scale) {
  __shared__ u16 As[128 * 32];
  __shared__ u16 Bs[128 * 32];
  const int tid = threadIdx.x;
  const int w = tid >> 6, lane = tid & 63;
  const int wr = (w >> 1) * 64, wc = (w & 1) * 64;
  const int l15 = lane & 15, g = lane >> 4;
  const int m0 = blockIdx.x * 128, n0 = blockIdx.y * 128;

  floatx4 acc[4][4] = {};

  const u16* ga = A + (size_t)(m0 + (tid >> 2)) * C_ + (tid & 3) * 8;
  const u16* gb = Wt + (size_t)(n0 + (tid >> 2)) * C_ + (tid & 3) * 8;
  u16* lA = As + tid * 8;
  u16* lB = Bs + tid * 8;

  for (int kt = 0; kt < C_; kt += 32) {
    gload16(ga + kt, lA);
    gload16(ga + kt + (size_t)64 * C_, lA + 64 * 32);
    gload16(gb + kt, lB);
    gload16(gb + kt + (size_t)64 * C_, lB + 64 * 32);
    asm volatile("s_waitcnt vmcnt(0)" ::: "memory");
    __syncthreads();
    short8 af[4], bf[4];
#pragma unroll
    for (int i = 0; i < 4; ++i)
      af[i] = *(const short8*)(As + (wr + i * 16 + l15) * 32 + g * 8);
#pragma unroll
    for (int i = 0; i < 4; ++i)
      bf[i] = *(const short8*)(Bs + (wc + i * 16 + l15) * 32 + g * 8);
#pragma unroll
    for (int mi = 0; mi < 4; ++mi)
#pragma unroll
      for (int ni = 0; ni < 4; ++ni)
        acc[mi][ni] = __builtin_amdgcn_mfma_f32_16x16x32_bf16(af[mi], bf[ni], acc[mi][ni], 0, 0, 0);
    __syncthreads();
  }
#pragma unroll
  for (int mi = 0; mi < 4; ++mi) {
    int row = m0 + wr + mi * 16 + g * 4;
#pragma unroll
    for (int ni = 0; ni < 4; ++ni) {
      int col = n0 + wc + ni * 16 + l15;
      float bv = bias[col];
#pragma unroll
      for (int i = 0; i < 4; ++i) {
        float v = (acc[mi][ni][i] + bv) * scale;
        if (OUTF32)
          ((float*)Cout)[(size_t)(row + i) * C_ + col] = v;
        else
          ((u16*)Cout)[(size_t)(row + i) * C_ + col] = f2bf(v);
      }
    }
  }
}

// ------------- causal flash attention -------------
// grid: (T/64 q-tiles, B*H). 4 waves; wave w owns q rows [q0+16w, q0+16w+16).
// Q,K tiles: [64][64] bf16 in LDS, XOR-swizzled rows (byte ^= (row&7)<<4) via
// pre-swizzled global source + linear global_load_lds. V transposed to [d][kv]
// with same swizzle (reg-staged). P round-trips via wave-private swizzled LDS.
__global__ __launch_bounds__(256, 2) void attn_k(const u16* __restrict__ Qg,
                                                 const u16* __restrict__ Kg,
                                                 const u16* __restrict__ Vg,
                                                 u16* __restrict__ Yg) {
  __shared__ u16 Qs[64 * 64];
  __shared__ u16 Ks[64 * 64];
  __shared__ u16 Vt[64 * 64];
  __shared__ u16 Ps[4][16 * 64];
  const int tid = threadIdx.x;
  const int w = tid >> 6, lane = tid & 63;
  const int l15 = lane & 15, g = lane >> 4;
  const int q0 = blockIdx.x * 64;
  const int bh = blockIdx.y;
  const size_t base = (size_t)(bh >> 4) * T_ * C_ + (size_t)(bh & 15) * D_;

  const int srow = tid >> 3;    // 0..31 (staging row, +32 for 2nd round)
  const int schunk = tid & 7;
  const int sgcol = (schunk ^ (srow & 7)) * 8;  // pre-swizzled source column

  gload16(Qg + base + (size_t)(q0 + srow) * C_ + sgcol, (u16*)Qs + tid * 8);
  gload16(Qg + base + (size_t)(q0 + srow + 32) * C_ + sgcol, (u16*)Qs + (256 + tid) * 8);
  asm volatile("s_waitcnt vmcnt(0)" ::: "memory");
  __syncthreads();

  short8 qf0, qf1;
  {
    int row = w * 16 + l15;
    int sw = (row & 7) << 4;
    const char* qb = (const char*)Qs + row * 128;
    qf0 = *(const short8*)(qb + ((g * 16) ^ sw));
    qf1 = *(const short8*)(qb + ((g * 16 + 64) ^ sw));
  }

  floatx4 yacc[4] = {};
  float mrun[4], lrun[4];
#pragma unroll
  for (int i = 0; i < 4; ++i) { mrun[i] = -1e30f; lrun[i] = 0.f; }

  const int ntiles = blockIdx.x + 1;
  for (int t = 0; t < ntiles; ++t) {
    const int kv0 = t * 64;
    gload16(Kg + base + (size_t)(kv0 + srow) * C_ + sgcol, (u16*)Ks + tid * 8);
    gload16(Kg + base + (size_t)(kv0 + srow + 32) * C_ + sgcol, (u16*)Ks + (256 + tid) * 8);
    {
      int kvl = srow;
      int d0 = schunk * 8;
      ushort8_t va = *(const ushort8_t*)(Vg + base + (size_t)(kv0 + kvl) * C_ + d0);
      ushort8_t vb = *(const ushort8_t*)(Vg + base + (size_t)(kv0 + kvl + 32) * C_ + d0);
#pragma unroll
      for (int j = 0; j < 8; ++j) {
        int d = d0 + j;
        char* vr = (char*)Vt + d * 128;
        int sw = (d & 7) << 4;
        *(u16*)(vr + ((2 * kvl) ^ sw)) = va[j];
        *(u16*)(vr + ((2 * (kvl + 32)) ^ sw)) = vb[j];
      }
    }
    asm volatile("s_waitcnt vmcnt(0)" ::: "memory");
    __syncthreads();

    // S = Q @ K^T  (per wave: 16 q-rows x 64 kv)
    floatx4 sacc[4] = {};
    {
      int sw = (l15 & 7) << 4;
#pragma unroll
      for (int cb = 0; cb < 4; ++cb) {
        const char* kb = (const char*)Ks + (cb * 16 + l15) * 128;
        short8 k0 = *(const short8*)(kb + ((g * 16) ^ sw));
        short8 k1 = *(const short8*)(kb + ((g * 16 + 64) ^ sw));
        sacc[cb] = __builtin_amdgcn_mfma_f32_16x16x32_bf16(qf0, k0, sacc[cb], 0, 0, 0);
        sacc[cb] = __builtin_amdgcn_mfma_f32_16x16x32_bf16(qf1, k1, sacc[cb], 0, 0, 0);
      }
    }
    if (t == ntiles - 1) {  // diagonal tile: kv0 == q0
#pragma unroll
      for (int cb = 0; cb < 4; ++cb) {
        int kvc = cb * 16 + l15;
#pragma unroll
        for (int i = 0; i < 4; ++i) {
          int qr = w * 16 + g * 4 + i;
          if (kvc > qr) sacc[cb][i] = -1e30f;
        }
      }
    }
    // online softmax (rows live in 16-lane groups)
    float pm[4], rsum[4];
#pragma unroll
    for (int i = 0; i < 4; ++i)
      pm[i] = fmaxf(fmaxf(sacc[0][i], sacc[1][i]), fmaxf(sacc[2][i], sacc[3][i]));
#pragma unroll
    for (int mm = 1; mm < 16; mm <<= 1)
#pragma unroll
      for (int i = 0; i < 4; ++i) pm[i] = fmaxf(pm[i], __shfl_xor(pm[i], mm));
#pragma unroll
    for (int i = 0; i < 4; ++i) {
      float mn = fmaxf(mrun[i], pm[i]);
      float corr = exp2f((mrun[i] - mn) * 1.44269504f);
      mrun[i] = mn;
      lrun[i] *= corr;
#pragma unroll
      for (int ni = 0; ni < 4; ++ni) yacc[ni][i] *= corr;
      rsum[i] = 0.f;
    }
#pragma unroll
    for (int cb = 0; cb < 4; ++cb) {
      int colb = 32 * cb + 2 * l15;
#pragma unroll
      for (int i = 0; i < 4; ++i) {
        float p = exp2f((sacc[cb][i] - mrun[i]) * 1.44269504f);
        rsum[i] += p;
        int row = g * 4 + i;
        *(u16*)((char*)Ps[w] + row * 128 + (colb ^ ((row & 7) << 4))) = f2bf(p);
      }
    }
#pragma unroll
    for (int mm = 1; mm < 16; mm <<= 1)
#pragma unroll
      for (int i = 0; i < 4; ++i) rsum[i] += __shfl_xor(rsum[i], mm);
#pragma unroll
    for (int i = 0; i < 4; ++i) lrun[i] += rsum[i];

    asm volatile("s_waitcnt lgkmcnt(0)" ::: "memory");
    __builtin_amdgcn_sched_barrier(0);

    short8 pf0, pf1;
    {
      int sw = (l15 & 7) << 4;
      const char* pb = (const char*)Ps[w] + l15 * 128;
      pf0 = *(const short8*)(pb + ((g * 16) ^ sw));
      pf1 = *(const short8*)(pb + ((g * 16 + 64) ^ sw));
    }
#pragma unroll
    for (int ni = 0; ni < 4; ++ni) {
      int d = ni * 16 + l15;
      int sw = (d & 7) << 4;
      const char* vr = (const char*)Vt + d * 128;
      short8 v0 = *(const short8*)(vr + ((g * 16) ^ sw));
      short8 v1 = *(const short8*)(vr + ((g * 16 + 64) ^ sw));
      yacc[ni] = __builtin_amdgcn_mfma_f32_16x16x32_bf16(pf0, v0, yacc[ni], 0, 0, 0);
      yacc[ni] = __builtin_amdgcn_mfma_f32_16x16x32_bf16(pf1, v1, yacc[ni], 0, 0, 0);
    }
    __syncthreads();
  }

#pragma unroll
  for (int i = 0; i < 4; ++i) {
    float inv = 1.0f / lrun[i];
    int trow = q0 + w * 16 + g * 4 + i;
#pragma unroll
    for (int ni = 0; ni < 4; ++ni) {
      int d = ni * 16 + l15;
      Yg[base + (size_t)trow * C_ + d] = f2bf(yacc[ni][i] * inv);
    }
  }
}

extern "C" void kernel_launch(void* const* d_in, const int* in_sizes, int n_in,
                              void* d_out, int out_size, void* d_ws, size_t ws_size,
                              hipStream_t stream) {
  const float* x  = (const float*)d_in[0];
  const float* Wq = (const float*)d_in[1];
  const float* bq = (const float*)d_in[2];
  const float* Wk = (const float*)d_in[3];
  const float* bk = (const float*)d_in[4];
  const float* Wv = (const float*)d_in[5];
  const float* bv = (const float*)d_in[6];
  const float* Wo = (const float*)d_in[7];
  const float* bo = (const float*)d_in[8];
  float* out = (float*)d_out;

  char* ws = (char*)d_ws;
  u16* xb = (u16*)ws;                                  // 16 MiB (reused as Yb after QKV GEMMs)
  u16* WT = (u16*)(ws + (size_t)16777216);             // 4 x 2 MiB
  u16* Qb = (u16*)(ws + (size_t)25165824);             // 16 MiB
  u16* Kb = (u16*)(ws + (size_t)41943040);             // 16 MiB
  u16* Vb = (u16*)(ws + (size_t)58720256);             // 16 MiB  (end: 72 MiB)
  u16* Yb = xb;  // x is dead after the V projection; attn writes Y here

  convx_k<<<dim3(M_ * C_ / 1024), 256, 0, stream>>>(x, xb);
  wconv_k<<<dim3(16, 16, 4), 256, 0, stream>>>(Wq, Wk, Wv, Wo, WT);
  gemm_k<0><<<dim3(64, 8), 256, 0, stream>>>(xb, WT + (size_t)0 * 1048576, bq, Qb, 0.125f);
  gemm_k<0><<<dim3(64, 8), 256, 0, stream>>>(xb, WT + (size_t)1 * 1048576, bk, Kb, 1.0f);
  gemm_k<0><<<dim3(64, 8), 256, 0, stream>>>(xb, WT + (size_t)2 * 1048576, bv, Vb, 1.0f);
  attn_k<<<dim3(T_ / 64, B_ * H_), 256, 0, stream>>>(Qb, Kb, Vb, Yb);
  gemm_k<1><<<dim3(64, 8), 256, 0, stream>>>(Yb, WT + (size_t)3 * 1048576, bo, out, 1.0f);
}

// Round 2
// 197.742 us; speedup vs baseline: 2.1458x; 2.1458x over previous
//
#include <hip/hip_runtime.h>

#define B_ 4
#define T_ 2048
#define C_ 1024
#define H_ 16
#define D_ 64
#define M_ (B_*T_)   // 8192 rows

typedef unsigned short u16;
typedef __attribute__((ext_vector_type(8))) short short8;
typedef __attribute__((ext_vector_type(8))) unsigned short ushort8_t;
typedef __attribute__((ext_vector_type(4))) unsigned short ushort4_t;
typedef __attribute__((ext_vector_type(4))) float floatx4;
typedef __attribute__((ext_vector_type(16))) float f32x16;
typedef __attribute__((ext_vector_type(4))) unsigned int uint4_t;

__device__ __forceinline__ u16 f2bf(float f) {
  union { float f; unsigned u; } v; v.f = f;
  unsigned r = v.u + 0x7fffu + ((v.u >> 16) & 1u);
  return (u16)(r >> 16);
}

__device__ __forceinline__ void gload16(const void* g, void* l) {
  __builtin_amdgcn_global_load_lds((__attribute__((address_space(1))) void*)(g),
                                   (__attribute__((address_space(3))) void*)(l),
                                   16, 0, 0);
}

__device__ __forceinline__ unsigned cvtpk(float lo, float hi) {
  unsigned r;
  asm("v_cvt_pk_bf16_f32 %0, %1, %2" : "=v"(r) : "v"(lo), "v"(hi));
  return r;
}

__device__ __forceinline__ void pl32swap(unsigned &a, unsigned &b) {
  asm volatile("v_permlane32_swap_b32 %0, %1" : "+v"(a), "+v"(b));
}

// ---------------- x -> bf16 ----------------
__global__ __launch_bounds__(256) void convx_k(const float* __restrict__ x,
                                               u16* __restrict__ o) {
  int i = (blockIdx.x * 256 + threadIdx.x) * 4;
  floatx4 v = *(const floatx4*)(x + i);
  ushort4_t r;
#pragma unroll
  for (int j = 0; j < 4; ++j) r[j] = f2bf(v[j]);
  *(ushort4_t*)(o + i) = r;
}

// ------------- W (K x N) -> WT (N x K) bf16, LDS-tiled transpose -------------
__global__ __launch_bounds__(256) void wconv_k(const float* __restrict__ W0,
                                               const float* __restrict__ W1,
                                               const float* __restrict__ W2,
                                               const float* __restrict__ W3,
                                               u16* __restrict__ WT) {
  __shared__ float tile[64][65];
  const float* W = blockIdx.z == 0 ? W0 : blockIdx.z == 1 ? W1 : blockIdx.z == 2 ? W2 : W3;
  u16* Wt = WT + (size_t)blockIdx.z * (C_ * C_);
  int k0 = blockIdx.x * 64, n0 = blockIdx.y * 64;
  int t = threadIdx.x;
  int r = t >> 2, c0 = (t & 3) * 16;
#pragma unroll
  for (int j = 0; j < 4; ++j) {
    floatx4 v = *(const floatx4*)(W + (size_t)(k0 + r) * C_ + n0 + c0 + j * 4);
#pragma unroll
    for (int jj = 0; jj < 4; ++jj) tile[r][c0 + j * 4 + jj] = v[jj];
  }
  __syncthreads();
  ushort8_t o0, o1;
#pragma unroll
  for (int j = 0; j < 8; ++j) o0[j] = f2bf(tile[c0 + j][r]);
#pragma unroll
  for (int j = 0; j < 8; ++j) o1[j] = f2bf(tile[c0 + 8 + j][r]);
  *(ushort8_t*)(Wt + (size_t)(n0 + r) * C_ + k0 + c0) = o0;
  *(ushort8_t*)(Wt + (size_t)(n0 + r) * C_ + k0 + c0 + 8) = o1;
}

// ------------- GEMM: C[M,N] = A[M,K] @ WT[N,K]^T + bias, N=K=1024 -------------
template <int OUTF32>
__global__ __launch_bounds__(256, 2) void gemm_k(const u16* __restrict__ A,
                                                 const u16* __restrict__ Wt,
                                                 const float* __restrict__ bias,
                                                 void* __restrict__ Cout, float scale) {
  __shared__ u16 As[128 * 32];
  __shared__ u16 Bs[128 * 32];
  const int tid = threadIdx.x;
  const int w = tid >> 6, lane = tid & 63;
  const int wr = (w >> 1) * 64, wc = (w & 1) * 64;
  const int l15 = lane & 15, g = lane >> 4;
  const int m0 = blockIdx.x * 128, n0 = blockIdx.y * 128;

  floatx4 acc[4][4] = {};

  const u16* ga = A + (size_t)(m0 + (tid >> 2)) * C_ + (tid & 3) * 8;
  const u16* gb = Wt + (size_t)(n0 + (tid >> 2)) * C_ + (tid & 3) * 8;
  u16* lA = As + tid * 8;
  u16* lB = Bs + tid * 8;

  for (int kt = 0; kt < C_; kt += 32) {
    gload16(ga + kt, lA);
    gload16(ga + kt + (size_t)64 * C_, lA + 64 * 32);
    gload16(gb + kt, lB);
    gload16(gb + kt + (size_t)64 * C_, lB + 64 * 32);
    asm volatile("s_waitcnt vmcnt(0)" ::: "memory");
    __syncthreads();
    short8 af[4], bf[4];
#pragma unroll
    for (int i = 0; i < 4; ++i)
      af[i] = *(const short8*)(As + (wr + i * 16 + l15) * 32 + g * 8);
#pragma unroll
    for (int i = 0; i < 4; ++i)
      bf[i] = *(const short8*)(Bs + (wc + i * 16 + l15) * 32 + g * 8);
#pragma unroll
    for (int mi = 0; mi < 4; ++mi)
#pragma unroll
      for (int ni = 0; ni < 4; ++ni)
        acc[mi][ni] = __builtin_amdgcn_mfma_f32_16x16x32_bf16(af[mi], bf[ni], acc[mi][ni], 0, 0, 0);
    __syncthreads();
  }
#pragma unroll
  for (int mi = 0; mi < 4; ++mi) {
    int row = m0 + wr + mi * 16 + g * 4;
#pragma unroll
    for (int ni = 0; ni < 4; ++ni) {
      int col = n0 + wc + ni * 16 + l15;
      float bv = bias[col];
#pragma unroll
      for (int i = 0; i < 4; ++i) {
        float v = (acc[mi][ni][i] + bv) * scale;
        if (OUTF32)
          ((float*)Cout)[(size_t)(row + i) * C_ + col] = v;
        else
          ((u16*)Cout)[(size_t)(row + i) * C_ + col] = f2bf(v);
      }
    }
  }
}

// ------------- causal flash attention, 8-wave 32x32 swapped-QK structure ------
// grid logical: 8 q-tiles (256 rows) x 64 (b,h); heavy-first + XCD-chunked remap.
// Per warp: 32 q-rows. KVBLK=64. Swapped QK^T (mfma(K,Q)) -> lane owns q=lane&31.
// In-register softmax, cvt_pk+permlane32_swap P redistribution, defer-max,
// double-buffered async K/V staging (K: global_load_lds pre-swizzled; V: reg->
// LDS transposed+swizzled).
__global__ __launch_bounds__(512, 2) void attn_k(const u16* __restrict__ Qg,
                                                 const u16* __restrict__ Kg,
                                                 const u16* __restrict__ Vg,
                                                 u16* __restrict__ Yg) {
  __shared__ u16 Ks[2][64 * 64];
  __shared__ u16 Vt[2][64 * 64];

  const int tid = threadIdx.x;
  const int w = tid >> 6, lane = tid & 63;
  const int qi = lane & 31, h = lane >> 5;

  // block remap: heavy q-tiles first, heads chunked per XCD
  const int lid = blockIdx.x + 8 * blockIdx.y;   // grid (8,64), x fastest
  const int xcd = lid & 7, slot = lid >> 3;
  const int bxl = 7 - (slot >> 3);               // q-tile, heavy (7) first
  const int bh = xcd + 8 * (slot & 7);           // head group per XCD
  const int q0 = bxl * 256;
  const size_t base = (size_t)(bh >> 4) * ((size_t)T_ * C_) + (size_t)(bh & 15) * D_;
  const int qw0 = q0 + w * 32;
  const int q_abs = qw0 + qi;

  // staging roles (512 threads cover a full 64x64 tile in one shot)
  const int srow = tid >> 3, schunk = tid & 7;
  const int sgcol = (schunk ^ (srow & 7)) * 8;   // pre-swizzled source col (u16)
  const u16* Kgr = Kg + base + (size_t)srow * C_ + sgcol;
  const u16* Vgr = Vg + base + (size_t)srow * C_ + schunk * 8;

  // Q fragments: lane holds Q[q_abs][16c + 8h + j]
  short8 qf[4];
  {
    const u16* Qr = Qg + base + (size_t)q_abs * C_ + 8 * h;
#pragma unroll
    for (int c = 0; c < 4; ++c) qf[c] = *(const short8*)(Qr + 16 * c);
  }

  // prologue: issue tile-0 staging
  gload16(Kgr, &Ks[0][tid * 8]);
  ushort8_t va = *(const ushort8_t*)(Vgr);

  f32x16 y0 = {}, y1 = {};
  float m_run = -3e38f, l_run = 0.f;
  const int nt = 4 * bxl + 4;

  for (int t = 0; t < nt; ++t) {
    u16* Kb = Ks[t & 1];
    u16* Vb = Vt[t & 1];
    asm volatile("s_waitcnt vmcnt(0)" ::: "memory");
    // scatter V(t) regs -> Vt[buf] transposed + XOR-swizzled
#pragma unroll
    for (int j = 0; j < 8; ++j) {
      int d = schunk * 8 + j;
      *(u16*)((char*)Vb + d * 128 + ((2 * srow) ^ (j << 4))) = va[j];
    }
    __syncthreads();
    if (t + 1 < nt) {  // issue next tile's loads; they fly under this tile's compute
      gload16(Kgr + (size_t)(t + 1) * 64 * C_, &Ks[(t + 1) & 1][tid * 8]);
      va = *(const ushort8_t*)(Vgr + (size_t)(t + 1) * 64 * C_);
    }

    const int kv0 = t * 64;
    if (kv0 <= qw0 + 31) {  // warp has at least one unmasked kv in this tile
      // --- S^T = K @ Q^T : D[kv][q], q = lane&31 ---
      f32x16 s0 = {}, s1 = {};
      {
        const char* kbase = (const char*)Kb;
        const int sw = (qi & 7) << 4;
        const char* kr0 = kbase + qi * 128;
        const char* kr1 = kbase + (qi + 32) * 128;
#pragma unroll
        for (int c = 0; c < 4; ++c) {
          int col = (32 * c + 16 * h) ^ sw;
          short8 k0 = *(const short8*)(kr0 + col);
          short8 k1 = *(const short8*)(kr1 + col);
          s0 = __builtin_amdgcn_mfma_f32_32x32x16_bf16(k0, qf[c], s0, 0, 0, 0);
          s1 = __builtin_amdgcn_mfma_f32_32x32x16_bf16(k1, qf[c], s1, 0, 0, 0);
        }
      }
      // --- causal mask (exactly one crossing tile per warp) ---
      if (kv0 + 63 > qw0) {
#pragma unroll
        for (int r = 0; r < 16; ++r) {
          int kvq = (r & 3) + 8 * (r >> 2) + 4 * h;
          if (kv0 + kvq > q_abs) s0[r] = -1e30f;
          if (kv0 + 32 + kvq > q_abs) s1[r] = -1e30f;
        }
      }
      // --- online softmax (exp2 domain; log2e/8 folded into Q) ---
      float pm = s0[0];
#pragma unroll
      for (int r = 1; r < 16; ++r) pm = fmaxf(pm, s0[r]);
#pragma unroll
      for (int r = 0; r < 16; ++r) pm = fmaxf(pm, s1[r]);
      pm = fmaxf(pm, __shfl_xor(pm, 32));
      if (!__all(pm <= m_run + 8.0f)) {   // defer-max (T13)
        float mnew = fmaxf(m_run, pm);
        float corr = __builtin_amdgcn_exp2f(m_run - mnew);
        m_run = mnew;
        l_run *= corr;
#pragma unroll
        for (int r = 0; r < 16; ++r) {
          float cq = __shfl(corr, (r & 3) + 8 * (r >> 2) + 4 * h);
          y0[r] *= cq;
          y1[r] *= cq;
        }
      }
      float rs = 0.f;
#pragma unroll
      for (int r = 0; r < 16; ++r) { s0[r] = __builtin_amdgcn_exp2f(s0[r] - m_run); rs += s0[r]; }
#pragma unroll
      for (int r = 0; r < 16; ++r) { s1[r] = __builtin_amdgcn_exp2f(s1[r] - m_run); rs += s1[r]; }
      rs += __shfl_xor(rs, 32);
      l_run += rs;

      // --- P -> bf16 A-fragments via cvt_pk + permlane32_swap (T12) ---
      float pv[32];
#pragma unroll
      for (int r = 0; r < 16; ++r) { pv[r] = s0[r]; pv[16 + r] = s1[r]; }
      unsigned pw[16];
#pragma unroll
      for (int c = 0; c < 4; ++c) {
        const int rb = c * 8;
        unsigned a0 = cvtpk(pv[rb + 0], pv[rb + 1]);
        unsigned b0 = cvtpk(pv[rb + 4], pv[rb + 5]);
        pl32swap(a0, b0);
        unsigned a1 = cvtpk(pv[rb + 2], pv[rb + 3]);
        unsigned b1 = cvtpk(pv[rb + 6], pv[rb + 7]);
        pl32swap(a1, b1);
        pw[c * 4 + 0] = a0; pw[c * 4 + 1] = a1;
        pw[c * 4 + 2] = b0; pw[c * 4 + 3] = b1;
      }
      // --- PV: Y[q][d] += P @ V ---
      {
        const char* vb0 = (const char*)Vb + qi * 128;
        const char* vb1 = (const char*)Vb + (qi + 32) * 128;
        const int swd = (qi & 7) << 4;
#pragma unroll
        for (int c = 0; c < 4; ++c) {
          int col = (32 * c + 16 * h) ^ swd;
          uint4_t pt = {pw[c * 4 + 0], pw[c * 4 + 1], pw[c * 4 + 2], pw[c * 4 + 3]};
          short8 pa = __builtin_bit_cast(short8, pt);
          short8 v0 = *(const short8*)(vb0 + col);
          short8 v1 = *(const short8*)(vb1 + col);
          y0 = __builtin_amdgcn_mfma_f32_32x32x16_bf16(pa, v0, y0, 0, 0, 0);
          y1 = __builtin_amdgcn_mfma_f32_32x32x16_bf16(pa, v1, y1, 0, 0, 0);
        }
      }
    }
    __syncthreads();
  }

  // --- epilogue: normalize + store ---
  float linv = 1.0f / l_run;
#pragma unroll
  for (int r = 0; r < 16; ++r) {
    int qp = (r & 3) + 8 * (r >> 2) + 4 * h;
    float lv = __shfl(linv, qp);
    size_t row = base + (size_t)(qw0 + qp) * C_;
    Yg[row + qi] = f2bf(y0[r] * lv);
    Yg[row + 32 + qi] = f2bf(y1[r] * lv);
  }
}

extern "C" void kernel_launch(void* const* d_in, const int* in_sizes, int n_in,
                              void* d_out, int out_size, void* d_ws, size_t ws_size,
                              hipStream_t stream) {
  const float* x  = (const float*)d_in[0];
  const float* Wq = (const float*)d_in[1];
  const float* bq = (const float*)d_in[2];
  const float* Wk = (const float*)d_in[3];
  const float* bk = (const float*)d_in[4];
  const float* Wv = (const float*)d_in[5];
  const float* bv = (const float*)d_in[6];
  const float* Wo = (const float*)d_in[7];
  const float* bo = (const float*)d_in[8];
  float* out = (float*)d_out;

  char* ws = (char*)d_ws;
  u16* xb = (u16*)ws;                                  // 16 MiB (reused as Yb)
  u16* WT = (u16*)(ws + (size_t)16777216);             // 4 x 2 MiB
  u16* Qb = (u16*)(ws + (size_t)25165824);             // 16 MiB
  u16* Kb = (u16*)(ws + (size_t)41943040);             // 16 MiB
  u16* Vb = (u16*)(ws + (size_t)58720256);             // 16 MiB  (end: 72 MiB)
  u16* Yb = xb;

  convx_k<<<dim3(M_ * C_ / 1024), 256, 0, stream>>>(x, xb);
  wconv_k<<<dim3(16, 16, 4), 256, 0, stream>>>(Wq, Wk, Wv, Wo, WT);
  // Q scale folds softmax 1/sqrt(D) AND log2(e) for exp2-domain softmax
  gemm_k<0><<<dim3(64, 8), 256, 0, stream>>>(xb, WT + (size_t)0 * 1048576, bq, Qb, 0.125f * 1.44269504f);
  gemm_k<0><<<dim3(64, 8), 256, 0, stream>>>(xb, WT + (size_t)1 * 1048576, bk, Kb, 1.0f);
  gemm_k<0><<<dim3(64, 8), 256, 0, stream>>>(xb, WT + (size_t)2 * 1048576, bv, Vb, 1.0f);
  attn_k<<<dim3(8, 64), 512, 0, stream>>>(Qb, Kb, Vb, Yb);
  gemm_k<1><<<dim3(64, 8), 256, 0, stream>>>(Yb, WT + (size_t)3 * 1048576, bo, out, 1.0f);
}

// Round 3
// 190.442 us; speedup vs baseline: 2.2280x; 1.0383x over previous
//
#include <hip/hip_runtime.h>

#define B_ 4
#define T_ 2048
#define C_ 1024
#define H_ 16
#define D_ 64
#define M_ (B_*T_)   // 8192 rows
#define CR3 3072     // fused QKV row stride

typedef unsigned short u16;
typedef __attribute__((ext_vector_type(8))) short short8;
typedef __attribute__((ext_vector_type(8))) unsigned short ushort8_t;
typedef __attribute__((ext_vector_type(4))) unsigned short ushort4_t;
typedef __attribute__((ext_vector_type(4))) float floatx4;
typedef __attribute__((ext_vector_type(16))) float f32x16;
typedef __attribute__((ext_vector_type(4))) unsigned int uint4_t;

__device__ __forceinline__ u16 f2bf(float f) {
  union { float f; unsigned u; } v; v.f = f;
  unsigned r = v.u + 0x7fffu + ((v.u >> 16) & 1u);
  return (u16)(r >> 16);
}

__device__ __forceinline__ void gload16(const void* g, void* l) {
  __builtin_amdgcn_global_load_lds((__attribute__((address_space(1))) void*)(g),
                                   (__attribute__((address_space(3))) void*)(l),
                                   16, 0, 0);
}

__device__ __forceinline__ unsigned cvtpk(float lo, float hi) {
  unsigned r;
  asm("v_cvt_pk_bf16_f32 %0, %1, %2" : "=v"(r) : "v"(lo), "v"(hi));
  return r;
}

__device__ __forceinline__ void pl32swap(unsigned &a, unsigned &b) {
  asm volatile("v_permlane32_swap_b32 %0, %1" : "+v"(a), "+v"(b));
}

#define MFMA32(a, b, c) __builtin_amdgcn_mfma_f32_32x32x16_bf16(a, b, c, 0, 0, 0)

// ---------------- x -> bf16 ----------------
__global__ __launch_bounds__(256) void convx_k(const float* __restrict__ x,
                                               u16* __restrict__ o) {
  int i = (blockIdx.x * 256 + threadIdx.x) * 4;
  floatx4 v = *(const floatx4*)(x + i);
  ushort4_t r;
#pragma unroll
  for (int j = 0; j < 4; ++j) r[j] = f2bf(v[j]);
  *(ushort4_t*)(o + i) = r;
}

// ------------- W (K x N) -> WT (N x K) bf16 (Wq pre-scaled), LDS transpose ----
__global__ __launch_bounds__(256) void wconv_k(const float* __restrict__ W0,
                                               const float* __restrict__ W1,
                                               const float* __restrict__ W2,
                                               const float* __restrict__ W3,
                                               u16* __restrict__ WT) {
  __shared__ float tile[64][65];
  const float* W = blockIdx.z == 0 ? W0 : blockIdx.z == 1 ? W1 : blockIdx.z == 2 ? W2 : W3;
  const float sc = blockIdx.z == 0 ? 0.125f * 1.44269504f : 1.0f;  // 1/sqrt(D)*log2e into Wq
  u16* Wt = WT + (size_t)blockIdx.z * (C_ * C_);
  int k0 = blockIdx.x * 64, n0 = blockIdx.y * 64;
  int t = threadIdx.x;
  int r = t >> 2, c0 = (t & 3) * 16;
#pragma unroll
  for (int j = 0; j < 4; ++j) {
    floatx4 v = *(const floatx4*)(W + (size_t)(k0 + r) * C_ + n0 + c0 + j * 4);
#pragma unroll
    for (int jj = 0; jj < 4; ++jj) tile[r][c0 + j * 4 + jj] = v[jj];
  }
  __syncthreads();
  ushort8_t o0, o1;
#pragma unroll
  for (int j = 0; j < 8; ++j) o0[j] = f2bf(tile[c0 + j][r] * sc);
#pragma unroll
  for (int j = 0; j < 8; ++j) o1[j] = f2bf(tile[c0 + 8 + j][r] * sc);
  *(ushort8_t*)(Wt + (size_t)(n0 + r) * C_ + k0 + c0) = o0;
  *(ushort8_t*)(Wt + (size_t)(n0 + r) * C_ + k0 + c0 + 8) = o1;
}

// ---- GEMM: C[M,N] = A[M,1024] @ WT[N,1024]^T + bias(col-select), any N ------
template <int OUTF32>
__global__ __launch_bounds__(256, 2) void gemm_k(const u16* __restrict__ A,
                                                 const u16* __restrict__ Wt,
                                                 const float* __restrict__ b0,
                                                 const float* __restrict__ b1,
                                                 const float* __restrict__ b2,
                                                 float bsc0,
                                                 void* __restrict__ Cout, int ostride) {
  __shared__ u16 As[128 * 32];
  __shared__ u16 Bs[128 * 32];
  const int tid = threadIdx.x;
  const int w = tid >> 6, lane = tid & 63;
  const int wr = (w >> 1) * 64, wc = (w & 1) * 64;
  const int l15 = lane & 15, g = lane >> 4;
  const int m0 = blockIdx.x * 128, n0 = blockIdx.y * 128;

  floatx4 acc[4][4] = {};

  const u16* ga = A + (size_t)(m0 + (tid >> 2)) * C_ + (tid & 3) * 8;
  const u16* gb = Wt + (size_t)(n0 + (tid >> 2)) * C_ + (tid & 3) * 8;
  u16* lA = As + tid * 8;
  u16* lB = Bs + tid * 8;

  for (int kt = 0; kt < C_; kt += 32) {
    gload16(ga + kt, lA);
    gload16(ga + kt + (size_t)64 * C_, lA + 64 * 32);
    gload16(gb + kt, lB);
    gload16(gb + kt + (size_t)64 * C_, lB + 64 * 32);
    asm volatile("s_waitcnt vmcnt(0)" ::: "memory");
    __syncthreads();
    short8 af[4], bf[4];
#pragma unroll
    for (int i = 0; i < 4; ++i)
      af[i] = *(const short8*)(As + (wr + i * 16 + l15) * 32 + g * 8);
#pragma unroll
    for (int i = 0; i < 4; ++i)
      bf[i] = *(const short8*)(Bs + (wc + i * 16 + l15) * 32 + g * 8);
#pragma unroll
    for (int mi = 0; mi < 4; ++mi)
#pragma unroll
      for (int ni = 0; ni < 4; ++ni)
        acc[mi][ni] = __builtin_amdgcn_mfma_f32_16x16x32_bf16(af[mi], bf[ni], acc[mi][ni], 0, 0, 0);
    __syncthreads();
  }
#pragma unroll
  for (int mi = 0; mi < 4; ++mi) {
    int row = m0 + wr + mi * 16 + g * 4;
#pragma unroll
    for (int ni = 0; ni < 4; ++ni) {
      int col = n0 + wc + ni * 16 + l15;
      int seg = col >> 10;
      const float* bp = seg == 0 ? b0 : seg == 1 ? b1 : b2;
      float bv = bp[col & 1023] * (seg == 0 ? bsc0 : 1.0f);
#pragma unroll
      for (int i = 0; i < 4; ++i) {
        float v = acc[mi][ni][i] + bv;
        if (OUTF32)
          ((float*)Cout)[(size_t)(row + i) * ostride + col] = v;
        else
          ((u16*)Cout)[(size_t)(row + i) * ostride + col] = f2bf(v);
      }
    }
  }
}

// ------------- causal flash attention, folded q-tile pairs (uniform load) ----
// grid 512 x 256 thr (4 waves x 32 q-rows = 128-row q-tile per phase).
// Block p handles q-tiles jA=p (2p+2 kv-tiles) then jB=15-p (32-2p kv-tiles):
// 34 kv-tiles per block, ALWAYS -> balanced regardless of block->CU pairing.
__global__ __launch_bounds__(256, 2) void attn_k(const u16* __restrict__ QKV,
                                                 u16* __restrict__ Yg) {
  __shared__ u16 Ks[2][64 * 64];
  __shared__ u16 Vt[2][64 * 64];

  const int tid = threadIdx.x;
  const int w = tid >> 6, lane = tid & 63;
  const int qi = lane & 31, h = lane >> 5;

  const int lid = blockIdx.x;
  const int xcd = lid & 7, t2 = lid >> 3;
  const int bh = xcd + 8 * (t2 & 7);          // same head's 8 blocks share an XCD
  const int p = t2 >> 3;                      // fold pair 0..7
  const int jA = p, jB = 15 - p;
  const int nA = 2 * jA + 2;                  // even; nB = 32 - 2p; total 34

  const size_t baseQ = (size_t)(bh >> 4) * T_ * CR3 + (size_t)(bh & 15) * D_;
  const size_t baseY = (size_t)(bh >> 4) * T_ * C_ + (size_t)(bh & 15) * D_;
  const u16* Kg = QKV + baseQ + 1024;
  const u16* Vg = QKV + baseQ + 2048;

  const int srow = tid >> 3, schunk = tid & 7;
  const int sgcol = (schunk ^ (srow & 7)) * 8;
  const u16* Kgr = Kg + (size_t)srow * CR3 + sgcol;
  const u16* Vgr = Vg + (size_t)srow * CR3 + schunk * 8;

  // Q fragments for both phases (static names; rule #20)
  short8 qA0, qA1, qA2, qA3, qB0, qB1, qB2, qB3;
  {
    const u16* Qa = QKV + baseQ + (size_t)(128 * jA + 32 * w + qi) * CR3 + 8 * h;
    const u16* Qb = QKV + baseQ + (size_t)(128 * jB + 32 * w + qi) * CR3 + 8 * h;
    qA0 = *(const short8*)(Qa);      qA1 = *(const short8*)(Qa + 16);
    qA2 = *(const short8*)(Qa + 32); qA3 = *(const short8*)(Qa + 48);
    qB0 = *(const short8*)(Qb);      qB1 = *(const short8*)(Qb + 16);
    qB2 = *(const short8*)(Qb + 32); qB3 = *(const short8*)(Qb + 48);
  }

  ushort8_t va, vbr;
  // prologue: stage tile 0 (phase A, kv0=0)
  gload16(Kgr, &Ks[0][tid * 8]);
  gload16(Kgr + (size_t)32 * CR3, &Ks[0][2048 + tid * 8]);
  va = *(const ushort8_t*)(Vgr);
  vbr = *(const ushort8_t*)(Vgr + (size_t)32 * CR3);

  f32x16 y0 = {}, y1 = {};
  float m_run = -3e38f, l_run = 0.f;

#define PREFETCH(IT2) do { \
    if ((IT2) < 34) { \
      int nkv_ = ((IT2) >= nA ? (IT2) - nA : (IT2)) * 64; \
      u16* dst_ = Ks[(IT2) & 1]; \
      gload16(Kgr + (size_t)nkv_ * CR3, dst_ + tid * 8); \
      gload16(Kgr + (size_t)(nkv_ + 32) * CR3, dst_ + 2048 + tid * 8); \
      va = *(const ushort8_t*)(Vgr + (size_t)nkv_ * CR3); \
      vbr = *(const ushort8_t*)(Vgr + (size_t)(nkv_ + 32) * CR3); \
    } } while (0)

#define SCATTERV(VB) do { \
    char* vbp_ = (char*)(VB); \
    _Pragma("unroll") for (int j = 0; j < 8; ++j) { \
      int d_ = schunk * 8 + j; \
      *(u16*)(vbp_ + d_ * 128 + ((2 * srow) ^ (j << 4))) = va[j]; \
      *(u16*)(vbp_ + d_ * 128 + ((2 * (srow + 32)) ^ (j << 4))) = vbr[j]; \
    } } while (0)

#define COMPUTE(KB, VB, KV0, QW0, QF0, QF1, QF2, QF3) do { \
    const int q_abs_ = (QW0) + qi; \
    f32x16 s0 = {}, s1 = {}; \
    { const int swq_ = (qi & 7) << 4; \
      const char* kr0_ = (const char*)(KB) + qi * 128; \
      const char* kr1_ = (const char*)(KB) + (qi + 32) * 128; \
      short8 k0_, k1_; \
      k0_ = *(const short8*)(kr0_ + ((16 * h) ^ swq_)); \
      k1_ = *(const short8*)(kr1_ + ((16 * h) ^ swq_)); \
      s0 = MFMA32(k0_, QF0, s0); s1 = MFMA32(k1_, QF0, s1); \
      k0_ = *(const short8*)(kr0_ + ((32 + 16 * h) ^ swq_)); \
      k1_ = *(const short8*)(kr1_ + ((32 + 16 * h) ^ swq_)); \
      s0 = MFMA32(k0_, QF1, s0); s1 = MFMA32(k1_, QF1, s1); \
      k0_ = *(const short8*)(kr0_ + ((64 + 16 * h) ^ swq_)); \
      k1_ = *(const short8*)(kr1_ + ((64 + 16 * h) ^ swq_)); \
      s0 = MFMA32(k0_, QF2, s0); s1 = MFMA32(k1_, QF2, s1); \
      k0_ = *(const short8*)(kr0_ + ((96 + 16 * h) ^ swq_)); \
      k1_ = *(const short8*)(kr1_ + ((96 + 16 * h) ^ swq_)); \
      s0 = MFMA32(k0_, QF3, s0); s1 = MFMA32(k1_, QF3, s1); \
    } \
    if ((KV0) + 63 > (QW0)) { \
      _Pragma("unroll") for (int r = 0; r < 16; ++r) { \
        int kvq_ = (r & 3) + 8 * (r >> 2) + 4 * h; \
        if ((KV0) + kvq_ > q_abs_) s0[r] = -1e30f; \
        if ((KV0) + 32 + kvq_ > q_abs_) s1[r] = -1e30f; \
      } \
    } \
    float pm_ = s0[0]; \
    _Pragma("unroll") for (int r = 1; r < 16; ++r) pm_ = fmaxf(pm_, s0[r]); \
    _Pragma("unroll") for (int r = 0; r < 16; ++r) pm_ = fmaxf(pm_, s1[r]); \
    pm_ = fmaxf(pm_, __shfl_xor(pm_, 32)); \
    if (!__all(pm_ <= m_run + 8.0f)) { \
      float mnew_ = fmaxf(m_run, pm_); \
      float corr_ = __builtin_amdgcn_exp2f(m_run - mnew_); \
      m_run = mnew_; \
      l_run *= corr_; \
      _Pragma("unroll") for (int r = 0; r < 16; ++r) { \
        float cq_ = __shfl(corr_, (r & 3) + 8 * (r >> 2) + 4 * h); \
        y0[r] *= cq_; y1[r] *= cq_; \
      } \
    } \
    float rs_ = 0.f; \
    _Pragma("unroll") for (int r = 0; r < 16; ++r) { s0[r] = __builtin_amdgcn_exp2f(s0[r] - m_run); rs_ += s0[r]; } \
    _Pragma("unroll") for (int r = 0; r < 16; ++r) { s1[r] = __builtin_amdgcn_exp2f(s1[r] - m_run); rs_ += s1[r]; } \
    rs_ += __shfl_xor(rs_, 32); \
    l_run += rs_; \
    float pv_[32]; \
    _Pragma("unroll") for (int r = 0; r < 16; ++r) { pv_[r] = s0[r]; pv_[16 + r] = s1[r]; } \
    unsigned pw_[16]; \
    _Pragma("unroll") for (int c = 0; c < 4; ++c) { \
      const int rb_ = c * 8; \
      unsigned a0_ = cvtpk(pv_[rb_ + 0], pv_[rb_ + 1]); \
      unsigned b0_ = cvtpk(pv_[rb_ + 4], pv_[rb_ + 5]); \
      pl32swap(a0_, b0_); \
      unsigned a1_ = cvtpk(pv_[rb_ + 2], pv_[rb_ + 3]); \
      unsigned b1_ = cvtpk(pv_[rb_ + 6], pv_[rb_ + 7]); \
      pl32swap(a1_, b1_); \
      pw_[c * 4 + 0] = a0_; pw_[c * 4 + 1] = a1_; \
      pw_[c * 4 + 2] = b0_; pw_[c * 4 + 3] = b1_; \
    } \
    { const char* vb0_ = (const char*)(VB) + qi * 128; \
      const char* vb1_ = (const char*)(VB) + (qi + 32) * 128; \
      const int swd_ = (qi & 7) << 4; \
      _Pragma("unroll") for (int c = 0; c < 4; ++c) { \
        int col_ = (32 * c + 16 * h) ^ swd_; \
        uint4_t pt_ = {pw_[c * 4 + 0], pw_[c * 4 + 1], pw_[c * 4 + 2], pw_[c * 4 + 3]}; \
        short8 pa_ = __builtin_bit_cast(short8, pt_); \
        short8 v0_ = *(const short8*)(vb0_ + col_); \
        short8 v1_ = *(const short8*)(vb1_ + col_); \
        y0 = MFMA32(pa_, v0_, y0); \
        y1 = MFMA32(pa_, v1_, y1); \
      } \
    } } while (0)

#define STOREY(J) do { \
    float linv_ = 1.0f / l_run; \
    _Pragma("unroll") for (int r = 0; r < 16; ++r) { \
      int qp_ = (r & 3) + 8 * (r >> 2) + 4 * h; \
      float lv_ = __shfl(linv_, qp_); \
      size_t row_ = baseY + (size_t)(128 * (J) + 32 * w + qp_) * C_; \
      Yg[row_ + qi] = f2bf(y0[r] * lv_); \
      Yg[row_ + 32 + qi] = f2bf(y1[r] * lv_); \
    } } while (0)

  // ---- phase A (light tile jA) ----
  {
    const int qw0 = 128 * jA + 32 * w;
    for (int it = 0; it < nA; ++it) {
      const int kv0 = it * 64;
      u16* Kb = Ks[it & 1];
      u16* Vb = Vt[it & 1];
      asm volatile("s_waitcnt vmcnt(0)" ::: "memory");
      SCATTERV(Vb);
      __syncthreads();
      PREFETCH(it + 1);
      if (kv0 <= qw0 + 31) COMPUTE(Kb, Vb, kv0, qw0, qA0, qA1, qA2, qA3);
      __syncthreads();
    }
    STOREY(jA);
  }
  // reset online-softmax state
  y0 = (f32x16){}; y1 = (f32x16){};
  m_run = -3e38f; l_run = 0.f;
  // ---- phase B (heavy tile jB) ----
  {
    const int qw0 = 128 * jB + 32 * w;
    for (int it = nA; it < 34; ++it) {
      const int kv0 = (it - nA) * 64;
      u16* Kb = Ks[it & 1];
      u16* Vb = Vt[it & 1];
      asm volatile("s_waitcnt vmcnt(0)" ::: "memory");
      SCATTERV(Vb);
      __syncthreads();
      PREFETCH(it + 1);
      if (kv0 <= qw0 + 31) COMPUTE(Kb, Vb, kv0, qw0, qB0, qB1, qB2, qB3);
      __syncthreads();
    }
    STOREY(jB);
  }
}

extern "C" void kernel_launch(void* const* d_in, const int* in_sizes, int n_in,
                              void* d_out, int out_size, void* d_ws, size_t ws_size,
                              hipStream_t stream) {
  const float* x  = (const float*)d_in[0];
  const float* Wq = (const float*)d_in[1];
  const float* bq = (const float*)d_in[2];
  const float* Wk = (const float*)d_in[3];
  const float* bk = (const float*)d_in[4];
  const float* Wv = (const float*)d_in[5];
  const float* bv = (const float*)d_in[6];
  const float* Wo = (const float*)d_in[7];
  const float* bo = (const float*)d_in[8];
  float* out = (float*)d_out;

  char* ws = (char*)d_ws;
  u16* xb   = (u16*)ws;                           // 16 MiB (reused as Yb)
  u16* WT   = (u16*)(ws + (size_t)16777216);      // 4 x 2 MiB
  u16* QKVb = (u16*)(ws + (size_t)25165824);      // 8192 x 3072 x 2B = 48 MiB (end 73... )
  u16* Yb = xb;

  convx_k<<<dim3(M_ * C_ / 1024), 256, 0, stream>>>(x, xb);
  wconv_k<<<dim3(16, 16, 4), 256, 0, stream>>>(Wq, Wk, Wv, Wo, WT);
  // fused QKV projection: N = 3072 (Wq/bq pre-scaled by 1/sqrt(D)*log2e)
  gemm_k<0><<<dim3(64, 24), 256, 0, stream>>>(xb, WT, bq, bk, bv, 0.125f * 1.44269504f,
                                              QKVb, CR3);
  attn_k<<<dim3(512), 256, 0, stream>>>(QKVb, Yb);
  gemm_k<1><<<dim3(64, 8), 256, 0, stream>>>(Yb, WT + (size_t)3 * 1048576, bo, bo, bo, 1.0f,
                                             out, C_);
}

// Round 4
// 184.631 us; speedup vs baseline: 2.2982x; 1.0315x over previous
//
#include <hip/hip_runtime.h>

#define B_ 4
#define T_ 2048
#define C_ 1024
#define H_ 16
#define D_ 64
#define M_ (B_*T_)   // 8192 rows
#define CR3 3072     // fused QKV row stride

typedef unsigned short u16;
typedef __attribute__((ext_vector_type(8))) short short8;
typedef __attribute__((ext_vector_type(8))) unsigned short ushort8_t;
typedef __attribute__((ext_vector_type(4))) unsigned short ushort4_t;
typedef __attribute__((ext_vector_type(4))) float floatx4;
typedef __attribute__((ext_vector_type(16))) float f32x16;
typedef __attribute__((ext_vector_type(4))) unsigned int uint4_t;

__device__ __forceinline__ u16 f2bf(float f) {
  union { float f; unsigned u; } v; v.f = f;
  unsigned r = v.u + 0x7fffu + ((v.u >> 16) & 1u);
  return (u16)(r >> 16);
}

__device__ __forceinline__ void gload16(const void* g, void* l) {
  __builtin_amdgcn_global_load_lds((__attribute__((address_space(1))) void*)(g),
                                   (__attribute__((address_space(3))) void*)(l),
                                   16, 0, 0);
}

__device__ __forceinline__ unsigned cvtpk(float lo, float hi) {
  unsigned r;
  asm("v_cvt_pk_bf16_f32 %0, %1, %2" : "=v"(r) : "v"(lo), "v"(hi));
  return r;
}

__device__ __forceinline__ void pl32swap(unsigned &a, unsigned &b) {
  asm volatile("v_permlane32_swap_b32 %0, %1" : "+v"(a), "+v"(b));
}

#define MFMA32(a, b, c) __builtin_amdgcn_mfma_f32_32x32x16_bf16(a, b, c, 0, 0, 0)

// ---------------- x -> bf16 ----------------
__global__ __launch_bounds__(256) void convx_k(const float* __restrict__ x,
                                               u16* __restrict__ o) {
  int i = (blockIdx.x * 256 + threadIdx.x) * 4;
  floatx4 v = *(const floatx4*)(x + i);
  ushort4_t r;
#pragma unroll
  for (int j = 0; j < 4; ++j) r[j] = f2bf(v[j]);
  *(ushort4_t*)(o + i) = r;
}

// ------------- W (K x N) -> WT (N x K) bf16 (Wq pre-scaled), LDS transpose ----
__global__ __launch_bounds__(256) void wconv_k(const float* __restrict__ W0,
                                               const float* __restrict__ W1,
                                               const float* __restrict__ W2,
                                               const float* __restrict__ W3,
                                               u16* __restrict__ WT) {
  __shared__ float tile[64][65];
  const float* W = blockIdx.z == 0 ? W0 : blockIdx.z == 1 ? W1 : blockIdx.z == 2 ? W2 : W3;
  const float sc = blockIdx.z == 0 ? 0.125f * 1.44269504f : 1.0f;  // 1/sqrt(D)*log2e into Wq
  u16* Wt = WT + (size_t)blockIdx.z * (C_ * C_);
  int k0 = blockIdx.x * 64, n0 = blockIdx.y * 64;
  int t = threadIdx.x;
  int r = t >> 2, c0 = (t & 3) * 16;
#pragma unroll
  for (int j = 0; j < 4; ++j) {
    floatx4 v = *(const floatx4*)(W + (size_t)(k0 + r) * C_ + n0 + c0 + j * 4);
#pragma unroll
    for (int jj = 0; jj < 4; ++jj) tile[r][c0 + j * 4 + jj] = v[jj];
  }
  __syncthreads();
  ushort8_t o0, o1;
#pragma unroll
  for (int j = 0; j < 8; ++j) o0[j] = f2bf(tile[c0 + j][r] * sc);
#pragma unroll
  for (int j = 0; j < 8; ++j) o1[j] = f2bf(tile[c0 + 8 + j][r] * sc);
  *(ushort8_t*)(Wt + (size_t)(n0 + r) * C_ + k0 + c0) = o0;
  *(ushort8_t*)(Wt + (size_t)(n0 + r) * C_ + k0 + c0 + 8) = o1;
}

// ---- GEMM: C[M,N] = A[M,1024] @ WT[N,1024]^T + bias(col-select), any N ------
template <int OUTF32>
__global__ __launch_bounds__(256, 2) void gemm_k(const u16* __restrict__ A,
                                                 const u16* __restrict__ Wt,
                                                 const float* __restrict__ b0,
                                                 const float* __restrict__ b1,
                                                 const float* __restrict__ b2,
                                                 float bsc0,
                                                 void* __restrict__ Cout, int ostride) {
  __shared__ u16 As[128 * 32];
  __shared__ u16 Bs[128 * 32];
  const int tid = threadIdx.x;
  const int w = tid >> 6, lane = tid & 63;
  const int wr = (w >> 1) * 64, wc = (w & 1) * 64;
  const int l15 = lane & 15, g = lane >> 4;
  const int m0 = blockIdx.x * 128, n0 = blockIdx.y * 128;

  floatx4 acc[4][4] = {};

  const u16* ga = A + (size_t)(m0 + (tid >> 2)) * C_ + (tid & 3) * 8;
  const u16* gb = Wt + (size_t)(n0 + (tid >> 2)) * C_ + (tid & 3) * 8;
  u16* lA = As + tid * 8;
  u16* lB = Bs + tid * 8;

  for (int kt = 0; kt < C_; kt += 32) {
    gload16(ga + kt, lA);
    gload16(ga + kt + (size_t)64 * C_, lA + 64 * 32);
    gload16(gb + kt, lB);
    gload16(gb + kt + (size_t)64 * C_, lB + 64 * 32);
    asm volatile("s_waitcnt vmcnt(0)" ::: "memory");
    __syncthreads();
    short8 af[4], bf[4];
#pragma unroll
    for (int i = 0; i < 4; ++i)
      af[i] = *(const short8*)(As + (wr + i * 16 + l15) * 32 + g * 8);
#pragma unroll
    for (int i = 0; i < 4; ++i)
      bf[i] = *(const short8*)(Bs + (wc + i * 16 + l15) * 32 + g * 8);
#pragma unroll
    for (int mi = 0; mi < 4; ++mi)
#pragma unroll
      for (int ni = 0; ni < 4; ++ni)
        acc[mi][ni] = __builtin_amdgcn_mfma_f32_16x16x32_bf16(af[mi], bf[ni], acc[mi][ni], 0, 0, 0);
    __syncthreads();
  }
#pragma unroll
  for (int mi = 0; mi < 4; ++mi) {
    int row = m0 + wr + mi * 16 + g * 4;
#pragma unroll
    for (int ni = 0; ni < 4; ++ni) {
      int col = n0 + wc + ni * 16 + l15;
      int seg = col >> 10;
      const float* bp = seg == 0 ? b0 : seg == 1 ? b1 : b2;
      float bv = bp[col & 1023] * (seg == 0 ? bsc0 : 1.0f);
#pragma unroll
      for (int i = 0; i < 4; ++i) {
        float v = acc[mi][ni][i] + bv;
        if (OUTF32)
          ((float*)Cout)[(size_t)(row + i) * ostride + col] = v;
        else
          ((u16*)Cout)[(size_t)(row + i) * ostride + col] = f2bf(v);
      }
    }
  }
}

// ------------- causal flash attention -------------
// grid 1024 = 16 q-tiles x 64 heads, 4 blocks/CU resident. 4 waves x 32 q-rows.
// j-permutation: every stride-4 quadruple of (lid>>6) sums to 30 -> equal
// per-CU tile counts under round-robin block->CU placement.
// V LDS layout: Vt[d][kv], slot-XOR (d>>3)^(d&7) -> conflict-free scatter AND read.
// K LDS: slot-XOR (row&7) via pre-swizzled gload_lds source (m214 pattern).
__global__ __launch_bounds__(256, 4) void attn_k(const u16* __restrict__ QKV,
                                                 u16* __restrict__ Yg) {
  __shared__ u16 Ks[2][64 * 64];
  __shared__ u16 Vt[2][64 * 64];

  const int tid = threadIdx.x;
  const int w = tid >> 6, lane = tid & 63;
  const int qi = lane & 31, h = lane >> 5;

  const int lid = blockIdx.x;
  const int a4 = lid >> 6;                 // 0..15
  const int gq = a4 >> 2, iq = a4 & 3;
  // perm = {15,13,11,9, 0,2,4,6, 14,12,10,8, 1,3,5,7}
  const int jt = gq == 0 ? 15 - 2 * iq : gq == 1 ? 2 * iq : gq == 2 ? 14 - 2 * iq : 1 + 2 * iq;
  const int bh = lid & 63;
  const int nt = 2 * jt + 2;

  const size_t baseQ = (size_t)(bh >> 4) * T_ * CR3 + (size_t)(bh & 15) * D_;
  const size_t baseY = (size_t)(bh >> 4) * T_ * C_ + (size_t)(bh & 15) * D_;
  const u16* Kg = QKV + baseQ + 1024;
  const u16* Vg = QKV + baseQ + 2048;

  const int srow = tid >> 3, schunk = tid & 7;
  const int sgcol = (schunk ^ (srow & 7)) * 8;
  const u16* Kgr = Kg + (size_t)srow * CR3 + sgcol;
  const u16* Vgr = Vg + (size_t)srow * CR3 + schunk * 8;

  const int qw0 = 128 * jt + 32 * w;
  const int q_abs = qw0 + qi;

  // Q fragments
  short8 qf0, qf1, qf2, qf3;
  {
    const u16* Qr = QKV + baseQ + (size_t)q_abs * CR3 + 8 * h;
    qf0 = *(const short8*)(Qr);      qf1 = *(const short8*)(Qr + 16);
    qf2 = *(const short8*)(Qr + 32); qf3 = *(const short8*)(Qr + 48);
  }

  ushort8_t va, vbr;
  // prologue: stage tile 0
  gload16(Kgr, &Ks[0][tid * 8]);
  gload16(Kgr + (size_t)32 * CR3, &Ks[0][2048 + tid * 8]);
  va = *(const ushort8_t*)(Vgr);
  vbr = *(const ushort8_t*)(Vgr + (size_t)32 * CR3);

  f32x16 y0 = {}, y1 = {};
  float m_run = -3e38f, l_run = 0.f;

  for (int t = 0; t < nt; ++t) {
    const int kv0 = t * 64;
    u16* Kb = Ks[t & 1];
    u16* Vb = Vt[t & 1];
    asm volatile("s_waitcnt vmcnt(0)" ::: "memory");
    // scatter V(t) regs -> Vt[buf]; slot-XOR (d>>3)^(d&7) => conflict-free
    {
      char* vbp = (char*)Vb;
#pragma unroll
      for (int j = 0; j < 8; ++j) {
        int d = schunk * 8 + j;
        int sl = ((schunk ^ j) & 7) << 4;
        *(u16*)(vbp + d * 128 + ((2 * srow) ^ sl)) = va[j];
        *(u16*)(vbp + d * 128 + ((2 * (srow + 32)) ^ sl)) = vbr[j];
      }
    }
    __syncthreads();
    if (t + 1 < nt) {  // next tile's loads fly under this tile's compute
      int nkv = (t + 1) * 64;
      u16* dst = Ks[(t + 1) & 1];
      gload16(Kgr + (size_t)nkv * CR3, dst + tid * 8);
      gload16(Kgr + (size_t)(nkv + 32) * CR3, dst + 2048 + tid * 8);
      va = *(const ushort8_t*)(Vgr + (size_t)nkv * CR3);
      vbr = *(const ushort8_t*)(Vgr + (size_t)(nkv + 32) * CR3);
    }

    if (kv0 <= qw0 + 31) {
      // --- S^T = K @ Q^T ---
      f32x16 s0 = {}, s1 = {};
      {
        const int swq = (qi & 7) << 4;
        const char* kr0 = (const char*)Kb + qi * 128;
        const char* kr1 = (const char*)Kb + (qi + 32) * 128;
        short8 k0, k1;
        k0 = *(const short8*)(kr0 + ((16 * h) ^ swq));
        k1 = *(const short8*)(kr1 + ((16 * h) ^ swq));
        s0 = MFMA32(k0, qf0, s0); s1 = MFMA32(k1, qf0, s1);
        k0 = *(const short8*)(kr0 + ((32 + 16 * h) ^ swq));
        k1 = *(const short8*)(kr1 + ((32 + 16 * h) ^ swq));
        s0 = MFMA32(k0, qf1, s0); s1 = MFMA32(k1, qf1, s1);
        k0 = *(const short8*)(kr0 + ((64 + 16 * h) ^ swq));
        k1 = *(const short8*)(kr1 + ((64 + 16 * h) ^ swq));
        s0 = MFMA32(k0, qf2, s0); s1 = MFMA32(k1, qf2, s1);
        k0 = *(const short8*)(kr0 + ((96 + 16 * h) ^ swq));
        k1 = *(const short8*)(kr1 + ((96 + 16 * h) ^ swq));
        s0 = MFMA32(k0, qf3, s0); s1 = MFMA32(k1, qf3, s1);
      }
      // --- causal mask ---
      if (kv0 + 63 > qw0) {
#pragma unroll
        for (int r = 0; r < 16; ++r) {
          int kvq = (r & 3) + 8 * (r >> 2) + 4 * h;
          if (kv0 + kvq > q_abs) s0[r] = -1e30f;
          if (kv0 + 32 + kvq > q_abs) s1[r] = -1e30f;
        }
      }
      // --- online softmax (exp2 domain) ---
      float pm = s0[0];
#pragma unroll
      for (int r = 1; r < 16; ++r) pm = fmaxf(pm, s0[r]);
#pragma unroll
      for (int r = 0; r < 16; ++r) pm = fmaxf(pm, s1[r]);
      pm = fmaxf(pm, __shfl_xor(pm, 32));
      if (!__all(pm <= m_run + 8.0f)) {   // defer-max (T13)
        float mnew = fmaxf(m_run, pm);
        float corr = __builtin_amdgcn_exp2f(m_run - mnew);
        m_run = mnew;
        l_run *= corr;
#pragma unroll
        for (int r = 0; r < 16; ++r) {
          float cq = __shfl(corr, (r & 3) + 8 * (r >> 2) + 4 * h);
          y0[r] *= cq;
          y1[r] *= cq;
        }
      }
      float rs = 0.f;
#pragma unroll
      for (int r = 0; r < 16; ++r) { s0[r] = __builtin_amdgcn_exp2f(s0[r] - m_run); rs += s0[r]; }
#pragma unroll
      for (int r = 0; r < 16; ++r) { s1[r] = __builtin_amdgcn_exp2f(s1[r] - m_run); rs += s1[r]; }
      rs += __shfl_xor(rs, 32);
      l_run += rs;

      // --- P -> bf16 A-fragments via cvt_pk + permlane32_swap (T12) ---
      float pv[32];
#pragma unroll
      for (int r = 0; r < 16; ++r) { pv[r] = s0[r]; pv[16 + r] = s1[r]; }
      unsigned pw[16];
#pragma unroll
      for (int c = 0; c < 4; ++c) {
        const int rb = c * 8;
        unsigned a0 = cvtpk(pv[rb + 0], pv[rb + 1]);
        unsigned b0 = cvtpk(pv[rb + 4], pv[rb + 5]);
        pl32swap(a0, b0);
        unsigned a1 = cvtpk(pv[rb + 2], pv[rb + 3]);
        unsigned b1 = cvtpk(pv[rb + 6], pv[rb + 7]);
        pl32swap(a1, b1);
        pw[c * 4 + 0] = a0; pw[c * 4 + 1] = a1;
        pw[c * 4 + 2] = b0; pw[c * 4 + 3] = b1;
      }
      // --- PV: Y[q][d] += P @ V ---
      {
        const char* vb0 = (const char*)Vb + qi * 128;          // d = qi
        const char* vb1 = (const char*)Vb + (qi + 32) * 128;   // d = qi+32
        const int sx0 = (((qi >> 3) ^ qi) & 7) << 4;
        const int sx1 = sx0 ^ 0x40;
#pragma unroll
        for (int c = 0; c < 4; ++c) {
          int cb = 32 * c + 16 * h;
          uint4_t pt = {pw[c * 4 + 0], pw[c * 4 + 1], pw[c * 4 + 2], pw[c * 4 + 3]};
          short8 pa = __builtin_bit_cast(short8, pt);
          short8 v0 = *(const short8*)(vb0 + (cb ^ sx0));
          short8 v1 = *(const short8*)(vb1 + (cb ^ sx1));
          y0 = MFMA32(pa, v0, y0);
          y1 = MFMA32(pa, v1, y1);
        }
      }
    }
    __syncthreads();
  }

  // --- epilogue ---
  float linv = 1.0f / l_run;
#pragma unroll
  for (int r = 0; r < 16; ++r) {
    int qp = (r & 3) + 8 * (r >> 2) + 4 * h;
    float lv = __shfl(linv, qp);
    size_t row = baseY + (size_t)(qw0 + qp) * C_;
    Yg[row + qi] = f2bf(y0[r] * lv);
    Yg[row + 32 + qi] = f2bf(y1[r] * lv);
  }
}

extern "C" void kernel_launch(void* const* d_in, const int* in_sizes, int n_in,
                              void* d_out, int out_size, void* d_ws, size_t ws_size,
                              hipStream_t stream) {
  const float* x  = (const float*)d_in[0];
  const float* Wq = (const float*)d_in[1];
  const float* bq = (const float*)d_in[2];
  const float* Wk = (const float*)d_in[3];
  const float* bk = (const float*)d_in[4];
  const float* Wv = (const float*)d_in[5];
  const float* bv = (const float*)d_in[6];
  const float* Wo = (const float*)d_in[7];
  const float* bo = (const float*)d_in[8];
  float* out = (float*)d_out;

  char* ws = (char*)d_ws;
  u16* xb   = (u16*)ws;                           // 16 MiB (reused as Yb)
  u16* WT   = (u16*)(ws + (size_t)16777216);      // 4 x 2 MiB
  u16* QKVb = (u16*)(ws + (size_t)25165824);      // 8192 x 3072 x 2B = 48 MiB
  u16* Yb = xb;

  convx_k<<<dim3(M_ * C_ / 1024), 256, 0, stream>>>(x, xb);
  wconv_k<<<dim3(16, 16, 4), 256, 0, stream>>>(Wq, Wk, Wv, Wo, WT);
  // fused QKV projection: N = 3072 (Wq/bq pre-scaled by 1/sqrt(D)*log2e)
  gemm_k<0><<<dim3(64, 24), 256, 0, stream>>>(xb, WT, bq, bk, bv, 0.125f * 1.44269504f,
                                              QKVb, CR3);
  attn_k<<<dim3(1024), 256, 0, stream>>>(QKVb, Yb);
  gemm_k<1><<<dim3(64, 8), 256, 0, stream>>>(Yb, WT + (size_t)3 * 1048576, bo, bo, bo, 1.0f,
                                             out, C_);
}